// Round 3
// baseline (234.114 us; speedup 1.0000x reference)
//
#include <hip/hip_runtime.h>
#include <cstdint>

#define WIDTH 128
#define NCOMBO 2268   // 6*7*3*18 attr-combo rows
#define XSL 136       // bf16 LDS tile row stride (128 + 8 pad)
#define OSL 132       // f32 LDS tile row stride (128 + 4 pad)
#define TOTW (6 * 16384)
#define TOTU (3 * 34 * WIDTH)

typedef short bf16x8 __attribute__((ext_vector_type(8)));
typedef float f32x4  __attribute__((ext_vector_type(4)));

// gelu(v) = v * sigmoid(v*(1.5958+0.07135 v^2)); exp folded to exp2 (log2e
// pre-multiplied into the constants) -> saves the hidden mul in __expf.
__device__ __forceinline__ float gelu_fast(float v) {
    float e = __builtin_amdgcn_exp2f(v * __builtin_fmaf(v * v, 0.1029437f, 2.3022081f));
    return v - v * __builtin_amdgcn_rcpf(e + 1.0f);
}
__device__ __forceinline__ short f2b(float f) {
    unsigned u = __float_as_uint(f);
    unsigned r = (u + 0x7FFFu + ((u >> 16) & 1u)) >> 16;
    return (short)r;
}
__device__ __forceinline__ float b2f_lo(unsigned u) { return __uint_as_float(u << 16); }
__device__ __forceinline__ float b2f_hi(unsigned u) { return __uint_as_float(u & 0xFFFF0000u); }
__device__ __forceinline__ unsigned pack2(float lo, float hi) {
    return (unsigned)(unsigned short)f2b(lo) | ((unsigned)(unsigned short)f2b(hi) << 16);
}

// ---------------------------------------------------------------------------
// F1: (a) 6 weight mats -> bf16 fragment-order tables; (b) U tables
// [3][34][128] (bias folded into emb0 rows); (c) scal + done-counter reset;
// (d) HIST with rank (counts pre-zeroed by memset).  All parts independent.
// ---------------------------------------------------------------------------
__global__ void k_f1(const float* __restrict__ einit, const float* __restrict__ init0,
                     const float* __restrict__ emb0, const float* __restrict__ emb1,
                     const float* __restrict__ emb2, const float* __restrict__ emb3,
                     const float* __restrict__ r0w, const float* __restrict__ r0b,
                     const float* __restrict__ r1w, const float* __restrict__ r1b,
                     const float* __restrict__ r2w, const float* __restrict__ r2b,
                     const float* __restrict__ pw0, const float* __restrict__ pw1,
                     const float* __restrict__ pw2, const float* __restrict__ pw3,
                     const float* __restrict__ pw4, const float* __restrict__ pw5,
                     short* __restrict__ o0, short* __restrict__ o1,
                     short* __restrict__ o2, short* __restrict__ o3,
                     short* __restrict__ o4, short* __restrict__ o5,
                     float* __restrict__ U, float* __restrict__ scal,
                     const int* __restrict__ edge_index, int* __restrict__ counts,
                     int* __restrict__ rank, int* __restrict__ done, int E) {
    int tid = blockIdx.x * blockDim.x + threadIdx.x;
    if (tid == 0) { scal[0] = init0[0]; scal[1] = init0[1]; done[0] = 0; }
    if (tid < TOTW) {
        int which = tid >> 14;
        int r = tid & 16383;
        int t    = r >> 11;
        int kc   = (r >> 9) & 3;
        int lane = (r >> 3) & 63;
        int j    = r & 7;
        int k  = kc * 32 + ((lane >> 4) << 3) + j;
        int nn = (t << 4) + (lane & 15);
        const float* w = (which == 0) ? pw0 : (which == 1) ? pw1 : (which == 2) ? pw2
                       : (which == 3) ? pw3 : (which == 4) ? pw4 : pw5;
        short* o = (which == 0) ? o0 : (which == 1) ? o1 : (which == 2) ? o2
                 : (which == 3) ? o3 : (which == 4) ? o4 : o5;
        o[r] = f2b(w[k * 128 + nn]);
    } else if (tid < TOTW + TOTU) {
        int idx = tid - TOTW;
        float e0 = expf(einit[0]), e1 = expf(einit[1]), e2 = expf(einit[2]), e3 = expf(einit[3]);
        float inv = 1.0f / sqrtf(e0 + e1 + e2 + e3);
        float xw[4] = {e0 * inv, e1 * inv, e2 * inv, e3 * inv};
        float se = expf(init0[2]);
        float sv = expf(init0[3]);
        int r   = idx / (34 * WIDTH);
        int rem = idx - r * (34 * WIDTH);
        int g   = rem / WIDTH;
        int j   = rem - g * WIDTH;
        int cc, base;
        if (g >= 16)      { cc = 3; base = 16; }
        else if (g >= 13) { cc = 2; base = 13; }
        else if (g >= 6)  { cc = 1; base = 6; }
        else              { cc = 0; base = 0; }
        int i = g - base;
        const float* em = (cc == 0) ? emb0 : (cc == 1) ? emb1 : (cc == 2) ? emb2 : emb3;
        const float* w  = (r == 0) ? r0w : (r == 1) ? r1w : r2w;
        const float* rb = (r == 0) ? r0b : (r == 1) ? r1b : r2b;
        float s = (r == 2) ? sv : se;
        float acc = 0.0f;
        const float* erow = em + i * 64;
        for (int d = 0; d < 64; ++d) acc += erow[d] * w[d * WIDTH + j];
        float val = s * xw[cc] * acc;
        if (cc == 0) val += s * rb[j];
        U[idx] = val;
    } else if (tid < TOTW + TOTU + E) {
        int e = tid - TOTW - TOTU;
        rank[e] = atomicAdd(&counts[edge_index[E + e]], 1);
    }
}

// ---------------------------------------------------------------------------
// F2: blocks [0,sb): scan1 (block-local inclusive scan of counts) + the LAST
//     scan1 block to finish also performs scan2 (exclusive scan of block
//     totals, grand total -> offsets[n]).
//     blocks [sb,...): prepc — 2 combo-rows per 256-thread block.
// ---------------------------------------------------------------------------
__global__ void k_f2(const int* __restrict__ counts, int* __restrict__ lscan,
                     int* __restrict__ partials, int n, int sb,
                     const float* __restrict__ U, const float* __restrict__ init0,
                     float* __restrict__ Uc, int* __restrict__ done,
                     int* __restrict__ offsets) {
    if ((int)blockIdx.x < sb) {
        __shared__ int s[256];
        __shared__ int flag;
        int t = threadIdx.x;
        int i = blockIdx.x * 256 + t;
        int v = (i < n) ? counts[i] : 0;
        s[t] = v;
        __syncthreads();
        for (int d = 1; d < 256; d <<= 1) {
            int u = (t >= d) ? s[t - d] : 0;
            __syncthreads();
            s[t] += u;
            __syncthreads();
        }
        if (i < n) lscan[i] = s[t];
        if (t == 255) atomicExch(&partials[blockIdx.x], s[255]);
        __syncthreads();
        if (t == 0) {
            __threadfence();
            flag = (atomicAdd(done, 1) == sb - 1);
        }
        __syncthreads();
        if (flag) {
            // ---- scan2 tail: 4 partials per thread (sb <= 1024) ----
            __threadfence();
            int b0 = t * 4;
            int a0 = (b0     < sb) ? partials[b0]     : 0;
            int a1 = (b0 + 1 < sb) ? partials[b0 + 1] : 0;
            int a2 = (b0 + 2 < sb) ? partials[b0 + 2] : 0;
            int a3 = (b0 + 3 < sb) ? partials[b0 + 3] : 0;
            int tsum = a0 + a1 + a2 + a3;
            __syncthreads();
            s[t] = tsum;
            __syncthreads();
            for (int d = 1; d < 256; d <<= 1) {
                int u = (t >= d) ? s[t - d] : 0;
                __syncthreads();
                s[t] += u;
                __syncthreads();
            }
            int excl = s[t] - tsum;
            if (b0     < sb) partials[b0]     = excl;
            if (b0 + 1 < sb) partials[b0 + 1] = excl + a0;
            if (b0 + 2 < sb) partials[b0 + 2] = excl + a0 + a1;
            if (b0 + 3 < sb) partials[b0 + 3] = excl + a0 + a1 + a2;
            if (t == 255) offsets[n] = s[255];
        }
    } else {
        int bi = ((int)blockIdx.x - sb) * 2 + (threadIdx.x >> 7);
        if (bi >= 3 * NCOMBO) return;
        int r  = bi / NCOMBO;
        if (r < 2 && init0[0] == 0.0f) return;
        int cb = bi - r * NCOMBO;
        int a  = cb / 378;
        int rm = cb - a * 378;
        int b  = rm / 54;
        rm -= b * 54;
        int c  = rm / 18;
        int d  = rm - c * 18;
        int j  = threadIdx.x & 127;
        const float* Ur = U + r * 34 * WIDTH;
        Uc[(size_t)bi * WIDTH + j] = Ur[a * WIDTH + j] + Ur[(6 + b) * WIDTH + j]
                                   + Ur[(13 + c) * WIDTH + j] + Ur[(16 + d) * WIDTH + j];
    }
}

// ---------------------------------------------------------------------------
// F3: blocks [0,gb): gemm12 (pre GEMM + LN + 2/4 output GEMMs, coalesced).
//     blocks [gb,gb+eb): scatter (offsets computed inline — no dependency).
//     blocks [gb+eb,...): scan3 (write offsets[] for k_ap).
// ---------------------------------------------------------------------------
__global__ void __launch_bounds__(256, 2) k_f3(
        const float* __restrict__ x,
        const short* __restrict__ preF, const float* __restrict__ pre_b,
        const short* __restrict__ w0F, const float* __restrict__ b0,
        const short* __restrict__ w1F, const float* __restrict__ b1,
        const short* __restrict__ w2F, const float* __restrict__ b2,
        const short* __restrict__ w3F, const float* __restrict__ b3,
        const float* __restrict__ scal,
        short* __restrict__ Gb, float* __restrict__ A,
        short* __restrict__ Bb, short* __restrict__ Cb, int n,
        const int* __restrict__ edge_index, const int* __restrict__ edge_attr,
        const int* __restrict__ counts, const int* __restrict__ lscan,
        const int* __restrict__ partials, const int* __restrict__ rank,
        int* __restrict__ offsets, unsigned* __restrict__ s_pk, int E,
        int gb, int eb) {
    __shared__ short xs_raw[64 * XSL];
    __shared__ short xs_xx[64 * XSL];
    int tid = threadIdx.x;

    if ((int)blockIdx.x >= gb) {
        int rb = (int)blockIdx.x - gb;
        if (rb < eb) {
            // ---- scatter ----
            int e = rb * 256 + tid;
            if (e >= E) return;
            int src = edge_index[e];
            int dst = edge_index[E + e];
            int4 at = ((const int4*)edge_attr)[e];
            int combo = ((at.x * 7 + at.y) * 3 + at.z) * 18 + at.w;
            int off = partials[dst >> 8] + lscan[dst] - counts[dst];
            s_pk[off + rank[e]] = (unsigned)src | ((unsigned)combo << 17);
        } else {
            // ---- scan3: offsets[i] for k_ap ----
            int i = (rb - eb) * 256 + tid;
            if (i >= n) return;
            offsets[i] = partials[i >> 8] + lscan[i] - counts[i];
        }
        return;
    }

    // ---- gemm12 ----
    int w    = tid >> 6;
    int lane = tid & 63;
    int quad = lane >> 4, l16 = lane & 15;
    int m0   = blockIdx.x * 64;

    bf16x8 Bg[2][4], Bc[2][4];
#pragma unroll
    for (int tt = 0; tt < 2; ++tt)
#pragma unroll
        for (int kc = 0; kc < 4; ++kc) {
            int fo = (((2 * w + tt) * 4 + kc) * 64 + lane) * 8;
            Bg[tt][kc] = *(const bf16x8*)(w0F + fo);
            Bc[tt][kc] = *(const bf16x8*)(w3F + fo);
        }

#pragma unroll
    for (int it = 0; it < 8; ++it) {
        int fi  = it * 256 + tid;
        int row = fi >> 5, c4 = fi & 31;
        int gr  = min(m0 + row, n - 1);
        float4 v = ((const float4*)x)[(size_t)gr * 32 + c4];
        uint2 p;
        p.x = pack2(v.x, v.y);
        p.y = pack2(v.z, v.w);
        *(uint2*)(&xs_raw[row * XSL + c4 * 4]) = p;
    }
    __syncthreads();

    {
        bf16x8 a[4];
#pragma unroll
        for (int kc = 0; kc < 4; ++kc)
            a[kc] = *(const bf16x8*)(&xs_raw[(w * 16 + l16) * XSL + kc * 32 + quad * 8]);
        f32x4 acc[8];
#pragma unroll
        for (int t = 0; t < 8; ++t) acc[t] = (f32x4){0.f, 0.f, 0.f, 0.f};
#pragma unroll
        for (int kc = 0; kc < 4; ++kc)
#pragma unroll
            for (int t = 0; t < 8; ++t) {
                bf16x8 b = *(const bf16x8*)(preF + ((t * 4 + kc) * 64 + lane) * 8);
                acc[t] = __builtin_amdgcn_mfma_f32_16x16x32_bf16(a[kc], b, acc[t], 0, 0, 0);
            }
#pragma unroll
        for (int t = 0; t < 8; ++t) {
            float bv = pre_b[t * 16 + l16];
#pragma unroll
            for (int r = 0; r < 4; ++r) acc[t][r] += bv;
        }
#pragma unroll
        for (int r = 0; r < 4; ++r) {
            float s = 0.f, s2 = 0.f;
#pragma unroll
            for (int t = 0; t < 8; ++t) { float v = acc[t][r]; s += v; s2 += v * v; }
            s  += __shfl_xor(s, 1);  s2 += __shfl_xor(s2, 1);
            s  += __shfl_xor(s, 2);  s2 += __shfl_xor(s2, 2);
            s  += __shfl_xor(s, 4);  s2 += __shfl_xor(s2, 4);
            s  += __shfl_xor(s, 8);  s2 += __shfl_xor(s2, 8);
            float m   = s * (1.0f / WIDTH);
            float var = s2 * (1.0f / WIDTH) - m * m;
            float rs  = rsqrtf(var + 1e-5f);
#pragma unroll
            for (int t = 0; t < 8; ++t) acc[t][r] = (acc[t][r] - m) * rs;
        }
        int rowb = w * 16 + quad * 4;
#pragma unroll
        for (int t = 0; t < 8; ++t)
#pragma unroll
            for (int r = 0; r < 4; ++r)
                xs_xx[(rowb + r) * XSL + t * 16 + l16] = f2b(acc[t][r]);
    }
    __syncthreads();

    bf16x8 a2[4][4];
#pragma unroll
    for (int i = 0; i < 4; ++i)
#pragma unroll
        for (int kc = 0; kc < 4; ++kc)
            a2[i][kc] = *(const bf16x8*)(&xs_xx[(i * 16 + l16) * XSL + kc * 32 + quad * 8]);
    __syncthreads();

    {
        f32x4 accG[4][2], accC[4][2];
#pragma unroll
        for (int i = 0; i < 4; ++i)
#pragma unroll
            for (int tt = 0; tt < 2; ++tt) {
                accG[i][tt] = (f32x4){0.f,0.f,0.f,0.f};
                accC[i][tt] = (f32x4){0.f,0.f,0.f,0.f};
            }
#pragma unroll
        for (int kc = 0; kc < 4; ++kc)
#pragma unroll
            for (int i = 0; i < 4; ++i)
#pragma unroll
                for (int tt = 0; tt < 2; ++tt) {
                    accG[i][tt] = __builtin_amdgcn_mfma_f32_16x16x32_bf16(a2[i][kc], Bg[tt][kc], accG[i][tt], 0, 0, 0);
                    accC[i][tt] = __builtin_amdgcn_mfma_f32_16x16x32_bf16(a2[i][kc], Bc[tt][kc], accC[i][tt], 0, 0, 0);
                }
#pragma unroll
        for (int tt = 0; tt < 2; ++tt) {
            int col = (2 * w + tt) * 16 + l16;
            float bg = b0[col];
            float bc = b3[col];
#pragma unroll
            for (int i = 0; i < 4; ++i)
#pragma unroll
                for (int r = 0; r < 4; ++r) {
                    int row = i * 16 + quad * 4 + r;
                    xs_raw[row * XSL + col] = f2b(gelu_fast(accG[i][tt][r] + bg));
                    xs_xx[row * XSL + col]  = f2b(accC[i][tt][r] + bc);
                }
        }
    }
    __syncthreads();

#pragma unroll
    for (int it = 0; it < 4; ++it) {
        int si  = it * 256 + tid;
        int row = si >> 4, c8 = si & 15;
        if (m0 + row < n) {
            *(bf16x8*)(Gb + (size_t)(m0 + row) * WIDTH + c8 * 8) = *(const bf16x8*)(&xs_raw[row * XSL + c8 * 8]);
            *(bf16x8*)(Cb + (size_t)(m0 + row) * WIDTH + c8 * 8) = *(const bf16x8*)(&xs_xx[row * XSL + c8 * 8]);
        }
    }

    if (scal[0] != 0.0f) {
        bf16x8 Ba[2][4], Bbf[2][4];
#pragma unroll
        for (int tt = 0; tt < 2; ++tt)
#pragma unroll
            for (int kc = 0; kc < 4; ++kc) {
                int fo = (((2 * w + tt) * 4 + kc) * 64 + lane) * 8;
                Ba[tt][kc]  = *(const bf16x8*)(w1F + fo);
                Bbf[tt][kc] = *(const bf16x8*)(w2F + fo);
            }
        f32x4 accA[4][2], accB[4][2];
#pragma unroll
        for (int i = 0; i < 4; ++i)
#pragma unroll
            for (int tt = 0; tt < 2; ++tt) {
                accA[i][tt] = (f32x4){0.f,0.f,0.f,0.f};
                accB[i][tt] = (f32x4){0.f,0.f,0.f,0.f};
            }
#pragma unroll
        for (int kc = 0; kc < 4; ++kc)
#pragma unroll
            for (int i = 0; i < 4; ++i)
#pragma unroll
                for (int tt = 0; tt < 2; ++tt) {
                    accA[i][tt] = __builtin_amdgcn_mfma_f32_16x16x32_bf16(a2[i][kc], Ba[tt][kc],  accA[i][tt], 0, 0, 0);
                    accB[i][tt] = __builtin_amdgcn_mfma_f32_16x16x32_bf16(a2[i][kc], Bbf[tt][kc], accB[i][tt], 0, 0, 0);
                }
#pragma unroll
        for (int tt = 0; tt < 2; ++tt) {
            int col = (2 * w + tt) * 16 + l16;
            float ba = b1[col];
            float bb = b2[col];
#pragma unroll
            for (int i = 0; i < 4; ++i)
#pragma unroll
                for (int r = 0; r < 4; ++r) {
                    int row = m0 + i * 16 + quad * 4 + r;
                    if (row < n) {
                        size_t idx = (size_t)row * WIDTH + col;
                        A[idx]  = accA[i][tt][r] + ba;
                        Bb[idx] = f2b(accB[i][tt][r] + bb);
                    }
                }
        }
    }
}

// ---------------------------------------------------------------------------
// k_ap: FUSED aggregate + post-GEMM.  512 threads = 8 waves; 32 nodes/block.
// Agg phase: wave w owns rows w*4..w*4+3 (one node at a time, lane L owns
// cols {2L,2L+1}); per-node edge list is prefetched lane-parallel (one
// coalesced s_pk load per <=64 edges, then register-only v_readlane
// broadcasts) so all gathers of a node issue without intervening loads.
// h rows are packed bf16 into LDS; post phase does 32x128 @ 128x128 MFMA
// (2 tiles/wave, B frags loaded lazily to cap VGPR), staged f32 epilogue
// with residual.  Replaces k_agg + k_post: saves hb 12.8MB write + read
// and one launch.
// ---------------------------------------------------------------------------
__global__ void __launch_bounds__(512, 6)
k_ap(const int* __restrict__ offsets, const unsigned* __restrict__ s_pk,
     const float* __restrict__ A, const short* __restrict__ Bb,
     const short* __restrict__ Cb, const float* __restrict__ Uc,
     const float* __restrict__ scal, const short* __restrict__ Gb,
     const float* __restrict__ x, const short* __restrict__ postF,
     const float* __restrict__ post_b, float* __restrict__ out, int n) {
    __shared__ short hs[32 * XSL];
    __shared__ float os[32 * OSL];
    int tid = threadIdx.x;
    int w   = tid >> 6;
    int L   = tid & 63;
    int m0  = blockIdx.x * 32;

    const unsigned* Cb32 = (const unsigned*)Cb;
    const unsigned* Bb32 = (const unsigned*)Bb;
    const float2* U0c2 = (const float2*)(Uc);
    const float2* U1c2 = (const float2*)(Uc + (size_t)NCOMBO * WIDTH);
    const float2* U2c2 = (const float2*)(Uc + 2 * (size_t)NCOMBO * WIDTH);
    unsigned* hs32 = (unsigned*)hs;

    float i0 = scal[0], i1 = scal[1];
    float sE = __expf(i1);

    // ---- agg phase: 4 nodes per wave ----
    for (int k = 0; k < 4; ++k) {
        int row  = w * 4 + k;
        int node = m0 + row;
        float acc0 = 0.0f, acc1 = 0.0f;
        if (node < n) {
            int start = __builtin_amdgcn_readfirstlane(offsets[node]);
            int end   = __builtin_amdgcn_readfirstlane(offsets[node + 1]);
            if (i0 == 0.0f) {
                for (int base = start; base < end; base += 64) {
                    int cnt = min(end - base, 64);
                    unsigned pkv = (L < cnt) ? s_pk[base + L] : 0u;
                    int i = 0;
                    for (; i + 4 <= cnt; i += 4) {
                        unsigned pk0 = __builtin_amdgcn_readlane(pkv, i);
                        unsigned pk1 = __builtin_amdgcn_readlane(pkv, i + 1);
                        unsigned pk2 = __builtin_amdgcn_readlane(pkv, i + 2);
                        unsigned pk3 = __builtin_amdgcn_readlane(pkv, i + 3);
                        const unsigned* cp0 = Cb32 + ((size_t)(pk0 & 0x1FFFFu) << 6);
                        const unsigned* cp1 = Cb32 + ((size_t)(pk1 & 0x1FFFFu) << 6);
                        const unsigned* cp2 = Cb32 + ((size_t)(pk2 & 0x1FFFFu) << 6);
                        const unsigned* cp3 = Cb32 + ((size_t)(pk3 & 0x1FFFFu) << 6);
                        const float2* up0 = U2c2 + ((size_t)(pk0 >> 17) << 6);
                        const float2* up1 = U2c2 + ((size_t)(pk1 >> 17) << 6);
                        const float2* up2 = U2c2 + ((size_t)(pk2 >> 17) << 6);
                        const float2* up3 = U2c2 + ((size_t)(pk3 >> 17) << 6);
                        unsigned cc0 = cp0[L], cc1 = cp1[L], cc2 = cp2[L], cc3 = cp3[L];
                        float2   uu0 = up0[L], uu1 = up1[L], uu2 = up2[L], uu3 = up3[L];
                        acc0 += gelu_fast(b2f_lo(cc0) + uu0.x);
                        acc1 += gelu_fast(b2f_hi(cc0) + uu0.y);
                        acc0 += gelu_fast(b2f_lo(cc1) + uu1.x);
                        acc1 += gelu_fast(b2f_hi(cc1) + uu1.y);
                        acc0 += gelu_fast(b2f_lo(cc2) + uu2.x);
                        acc1 += gelu_fast(b2f_hi(cc2) + uu2.y);
                        acc0 += gelu_fast(b2f_lo(cc3) + uu3.x);
                        acc1 += gelu_fast(b2f_hi(cc3) + uu3.y);
                    }
                    for (; i < cnt; ++i) {
                        unsigned pk0 = __builtin_amdgcn_readlane(pkv, i);
                        const unsigned* cp0 = Cb32 + ((size_t)(pk0 & 0x1FFFFu) << 6);
                        const float2* up0 = U2c2 + ((size_t)(pk0 >> 17) << 6);
                        unsigned cc0 = cp0[L];
                        float2   uu0 = up0[L];
                        acc0 += gelu_fast(b2f_lo(cc0) + uu0.x);
                        acc1 += gelu_fast(b2f_hi(cc0) + uu0.y);
                    }
                }
                acc0 *= sE; acc1 *= sE;
            } else {
                float2 av = *(const float2*)(A + (size_t)node * WIDTH + 2 * L);
                for (int p = start; p < end; ++p) {
                    unsigned pk = s_pk[p];
                    unsigned sA = pk & 0x1FFFFu, cA = pk >> 17;
                    float2 u0 = U0c2[cA * 64 + L];
                    float2 u1 = U1c2[cA * 64 + L];
                    float2 u2 = U2c2[cA * 64 + L];
                    unsigned bb = Bb32[sA * 64 + L];
                    unsigned cc = Cb32[sA * 64 + L];
                    float q0 = av.x + u0.x, q1 = av.y + u0.y;
                    float k0 = b2f_lo(bb) + u1.x, k1 = b2f_hi(bb) + u1.y;
                    float v0 = gelu_fast(b2f_lo(cc) + u2.x);
                    float v1 = gelu_fast(b2f_hi(cc) + u2.y);
                    float s = q0 * k0 + q1 * k1;
                    s += __shfl_xor(s, 1);
                    s += __shfl_xor(s, 2);
                    s += __shfl_xor(s, 4);
                    s += __shfl_xor(s, 8);
                    s += __shfl_xor(s, 16);
                    float att = __expf(s * 0.125f * i0 + i1);
                    acc0 += v0 * att;
                    acc1 += v1 * att;
                }
            }
            unsigned g = ((const unsigned*)Gb)[(size_t)node * 64 + L];
            hs32[row * (XSL / 2) + L] = pack2(b2f_lo(g) + acc0, b2f_hi(g) + acc1);
        } else {
            hs32[row * (XSL / 2) + L] = 0u;
        }
    }
    __syncthreads();

    // ---- post phase: 32x128 @ 128x128, 2 tiles/wave ----
    int quad = L >> 4, l16 = L & 15;
    int ri    = w & 1;       // row tile 0..1
    int cpair = w >> 1;      // 0..3

    bf16x8 a[4];
#pragma unroll
    for (int kc = 0; kc < 4; ++kc)
        a[kc] = *(const bf16x8*)(&hs[(ri * 16 + l16) * XSL + kc * 32 + quad * 8]);

#pragma unroll
    for (int tt = 0; tt < 2; ++tt) {
        int t = cpair * 2 + tt;       // col tile 0..7
        f32x4 acc = (f32x4){0.f, 0.f, 0.f, 0.f};
#pragma unroll
        for (int kc = 0; kc < 4; ++kc) {
            bf16x8 b = *(const bf16x8*)(postF + ((t * 4 + kc) * 64 + L) * 8);
            acc = __builtin_amdgcn_mfma_f32_16x16x32_bf16(a[kc], b, acc, 0, 0, 0);
        }
        int col = t * 16 + l16;
        float bv = post_b[col];
#pragma unroll
        for (int r = 0; r < 4; ++r)
            os[(ri * 16 + quad * 4 + r) * OSL + col] = acc[r] + bv;
    }
    __syncthreads();

    // ---- epilogue: residual + coalesced out (32 rows x 32 float4) ----
#pragma unroll
    for (int it = 0; it < 2; ++it) {
        int fi  = it * 512 + tid;
        int row = fi >> 5, c4 = fi & 31;
        if (m0 + row < n) {
            float4 xv = ((const float4*)x)[(size_t)(m0 + row) * 32 + c4];
            float4 av = *(const float4*)(&os[row * OSL + c4 * 4]);
            float4 ov = {xv.x + av.x, xv.y + av.y, xv.z + av.z, xv.w + av.w};
            ((float4*)out)[(size_t)(m0 + row) * 32 + c4] = ov;
        }
    }
}

extern "C" void kernel_launch(void* const* d_in, const int* in_sizes, int n_in,
                              void* d_out, int out_size, void* d_ws, size_t ws_size,
                              hipStream_t stream) {
    const float* x      = (const float*)d_in[0];
    const int*   eidx   = (const int*)d_in[1];
    const int*   eattr  = (const int*)d_in[2];
    const float* pre_w  = (const float*)d_in[3];
    const float* pre_b  = (const float*)d_in[4];
    const float* msg0_w = (const float*)d_in[5];
    const float* msg0_b = (const float*)d_in[6];
    const float* msg1_w = (const float*)d_in[7];
    const float* msg1_b = (const float*)d_in[8];
    const float* msg2_w = (const float*)d_in[9];
    const float* msg2_b = (const float*)d_in[10];
    const float* msg3_w = (const float*)d_in[11];
    const float* msg3_b = (const float*)d_in[12];
    const float* r0w    = (const float*)d_in[13];
    const float* r0b    = (const float*)d_in[14];
    const float* r1w    = (const float*)d_in[15];
    const float* r1b    = (const float*)d_in[16];
    const float* r2w    = (const float*)d_in[17];
    const float* r2b    = (const float*)d_in[18];
    const float* post_w = (const float*)d_in[19];
    const float* post_b = (const float*)d_in[20];
    const float* emb0   = (const float*)d_in[21];
    const float* emb1   = (const float*)d_in[22];
    const float* emb2   = (const float*)d_in[23];
    const float* emb3   = (const float*)d_in[24];
    const float* einit  = (const float*)d_in[25];
    const float* init0  = (const float*)d_in[26];

    int n = in_sizes[0] / WIDTH;
    int E = in_sizes[2] / 4;
    size_t NW = (size_t)n * WIDTH;

    float* ws   = (float*)d_ws;
    float* A    = ws;                              // [N,128] f32 (full path only)
    float* U    = ws + NW;                         // [3][34][128]
    float* Uc   = U + 3 * 34 * WIDTH;              // [3][NCOMBO][128]
    float* scal = Uc + 3 * (size_t)NCOMBO * WIDTH; // [2]
    short* sw   = (short*)(scal + 2);
    short* preF  = sw;                             // 6 x 16384 bf16 frag-order weights
    short* w0F   = sw + 16384;
    short* w1F   = sw + 2 * 16384;
    short* w2F   = sw + 3 * 16384;
    short* w3F   = sw + 4 * 16384;
    short* postF = sw + 5 * 16384;
    short* Bb    = sw + 6 * 16384;                 // [N,128] bf16 (full path)
    short* Cb    = Bb + NW;                        // [N,128] bf16
    short* Gb    = Cb + NW;                        // [N,128] bf16
    int*      ib       = (int*)(Gb + NW);
    int*      offsets  = ib;                       // n+1
    int*      counts   = offsets + (n + 1);        // n
    int*      lscan    = counts + n;               // n
    int*      partials = lscan + n;                // <=1024
    int*      rank     = partials + 1024;          // E
    unsigned* s_pk     = (unsigned*)(rank + E);    // E
    int*      done     = (int*)(s_pk + E);         // 1 (scan2 last-block flag)

    hipMemsetAsync(counts, 0, (size_t)n * sizeof(int), stream);

    // F1: weight swizzle + U tables + hist(rank) + done reset
    int f1_total = TOTW + TOTU + E;
    k_f1<<<(f1_total + 255) / 256, 256, 0, stream>>>(
        einit, init0, emb0, emb1, emb2, emb3,
        r0w, r0b, r1w, r1b, r2w, r2b,
        pre_w, msg0_w, msg1_w, msg2_w, msg3_w, post_w,
        preF, w0F, w1F, w2F, w3F, postF, U, scal,
        eidx, counts, rank, done, E);

    // F2: scan1 (+ last-block scan2 tail) + prepc
    int sb  = (n + 255) / 256;
    int pcb = (3 * NCOMBO + 1) / 2;
    k_f2<<<sb + pcb, 256, 0, stream>>>(counts, lscan, partials, n, sb, U, init0, Uc,
                                       done, offsets);

    // F3: gemm12 + scatter (inline offsets) + scan3
    int gb = (n + 63) / 64;
    int eb = (E + 255) / 256;
    k_f3<<<gb + eb + sb, 256, 0, stream>>>(
        x, preF, pre_b, w0F, msg0_b, w1F, msg1_b, w2F, msg2_b, w3F, msg3_b,
        scal, Gb, A, Bb, Cb, n,
        eidx, eattr, counts, lscan, partials, rank, offsets, s_pk, E, gb, eb);

    // Fused aggregate + post
    k_ap<<<(n + 31) / 32, 512, 0, stream>>>(offsets, s_pk, A, Bb, Cb, Uc, scal, Gb,
                                            x, postF, post_b, (float*)d_out, n);
}

// Round 4
// 229.853 us; speedup vs baseline: 1.0185x; 1.0185x over previous
//
#include <hip/hip_runtime.h>
#include <cstdint>

#define WIDTH 128
#define NCOMBO 2268   // 6*7*3*18 attr-combo rows
#define XSL 136       // bf16 LDS tile row stride (128 + 8 pad)
#define OSL 132       // f32 LDS tile row stride (128 + 4 pad)
#define TOTW (6 * 16384)
#define TOTU (3 * 34 * WIDTH)

typedef short bf16x8 __attribute__((ext_vector_type(8)));
typedef float f32x4  __attribute__((ext_vector_type(4)));

// gelu(v) = v * sigmoid(v*(1.5958+0.07135 v^2)); exp folded to exp2 (log2e
// pre-multiplied into the constants) -> saves the hidden mul in __expf.
__device__ __forceinline__ float gelu_fast(float v) {
    float e = __builtin_amdgcn_exp2f(v * __builtin_fmaf(v * v, 0.1029437f, 2.3022081f));
    return v - v * __builtin_amdgcn_rcpf(e + 1.0f);
}
__device__ __forceinline__ short f2b(float f) {
    unsigned u = __float_as_uint(f);
    unsigned r = (u + 0x7FFFu + ((u >> 16) & 1u)) >> 16;
    return (short)r;
}
__device__ __forceinline__ float b2f_lo(unsigned u) { return __uint_as_float(u << 16); }
__device__ __forceinline__ float b2f_hi(unsigned u) { return __uint_as_float(u & 0xFFFF0000u); }
__device__ __forceinline__ unsigned pack2(float lo, float hi) {
    return (unsigned)(unsigned short)f2b(lo) | ((unsigned)(unsigned short)f2b(hi) << 16);
}

// ---------------------------------------------------------------------------
// F1: (a) 6 weight mats -> bf16 fragment-order tables; (b) U tables
// [3][34][128] (bias folded into emb0 rows); (c) scal + done-counter reset;
// (d) HIST with rank (counts pre-zeroed by memset).  All parts independent.
// ---------------------------------------------------------------------------
__global__ void k_f1(const float* __restrict__ einit, const float* __restrict__ init0,
                     const float* __restrict__ emb0, const float* __restrict__ emb1,
                     const float* __restrict__ emb2, const float* __restrict__ emb3,
                     const float* __restrict__ r0w, const float* __restrict__ r0b,
                     const float* __restrict__ r1w, const float* __restrict__ r1b,
                     const float* __restrict__ r2w, const float* __restrict__ r2b,
                     const float* __restrict__ pw0, const float* __restrict__ pw1,
                     const float* __restrict__ pw2, const float* __restrict__ pw3,
                     const float* __restrict__ pw4, const float* __restrict__ pw5,
                     short* __restrict__ o0, short* __restrict__ o1,
                     short* __restrict__ o2, short* __restrict__ o3,
                     short* __restrict__ o4, short* __restrict__ o5,
                     float* __restrict__ U, float* __restrict__ scal,
                     const int* __restrict__ edge_index, int* __restrict__ counts,
                     int* __restrict__ rank, int* __restrict__ done, int E) {
    int tid = blockIdx.x * blockDim.x + threadIdx.x;
    if (tid == 0) { scal[0] = init0[0]; scal[1] = init0[1]; done[0] = 0; }
    if (tid < TOTW) {
        int which = tid >> 14;
        int r = tid & 16383;
        int t    = r >> 11;
        int kc   = (r >> 9) & 3;
        int lane = (r >> 3) & 63;
        int j    = r & 7;
        int k  = kc * 32 + ((lane >> 4) << 3) + j;
        int nn = (t << 4) + (lane & 15);
        const float* w = (which == 0) ? pw0 : (which == 1) ? pw1 : (which == 2) ? pw2
                       : (which == 3) ? pw3 : (which == 4) ? pw4 : pw5;
        short* o = (which == 0) ? o0 : (which == 1) ? o1 : (which == 2) ? o2
                 : (which == 3) ? o3 : (which == 4) ? o4 : o5;
        o[r] = f2b(w[k * 128 + nn]);
    } else if (tid < TOTW + TOTU) {
        int idx = tid - TOTW;
        float e0 = expf(einit[0]), e1 = expf(einit[1]), e2 = expf(einit[2]), e3 = expf(einit[3]);
        float inv = 1.0f / sqrtf(e0 + e1 + e2 + e3);
        float xw[4] = {e0 * inv, e1 * inv, e2 * inv, e3 * inv};
        float se = expf(init0[2]);
        float sv = expf(init0[3]);
        int r   = idx / (34 * WIDTH);
        int rem = idx - r * (34 * WIDTH);
        int g   = rem / WIDTH;
        int j   = rem - g * WIDTH;
        int cc, base;
        if (g >= 16)      { cc = 3; base = 16; }
        else if (g >= 13) { cc = 2; base = 13; }
        else if (g >= 6)  { cc = 1; base = 6; }
        else              { cc = 0; base = 0; }
        int i = g - base;
        const float* em = (cc == 0) ? emb0 : (cc == 1) ? emb1 : (cc == 2) ? emb2 : emb3;
        const float* w  = (r == 0) ? r0w : (r == 1) ? r1w : r2w;
        const float* rb = (r == 0) ? r0b : (r == 1) ? r1b : r2b;
        float s = (r == 2) ? sv : se;
        float acc = 0.0f;
        const float* erow = em + i * 64;
        for (int d = 0; d < 64; ++d) acc += erow[d] * w[d * WIDTH + j];
        float val = s * xw[cc] * acc;
        if (cc == 0) val += s * rb[j];
        U[idx] = val;
    } else if (tid < TOTW + TOTU + E) {
        int e = tid - TOTW - TOTU;
        rank[e] = atomicAdd(&counts[edge_index[E + e]], 1);
    }
}

// ---------------------------------------------------------------------------
// F2: blocks [0,sb): scan1 (block-local inclusive scan of counts) + the LAST
//     scan1 block to finish also performs scan2 (exclusive scan of block
//     totals, grand total -> offsets[n]).
//     blocks [sb,...): prepc — 2 combo-rows per 256-thread block.
// ---------------------------------------------------------------------------
__global__ void k_f2(const int* __restrict__ counts, int* __restrict__ lscan,
                     int* __restrict__ partials, int n, int sb,
                     const float* __restrict__ U, const float* __restrict__ init0,
                     float* __restrict__ Uc, int* __restrict__ done,
                     int* __restrict__ offsets) {
    if ((int)blockIdx.x < sb) {
        __shared__ int s[256];
        __shared__ int flag;
        int t = threadIdx.x;
        int i = blockIdx.x * 256 + t;
        int v = (i < n) ? counts[i] : 0;
        s[t] = v;
        __syncthreads();
        for (int d = 1; d < 256; d <<= 1) {
            int u = (t >= d) ? s[t - d] : 0;
            __syncthreads();
            s[t] += u;
            __syncthreads();
        }
        if (i < n) lscan[i] = s[t];
        if (t == 255) atomicExch(&partials[blockIdx.x], s[255]);
        __syncthreads();
        if (t == 0) {
            __threadfence();
            flag = (atomicAdd(done, 1) == sb - 1);
        }
        __syncthreads();
        if (flag) {
            // ---- scan2 tail: 4 partials per thread (sb <= 1024) ----
            __threadfence();
            int b0 = t * 4;
            int a0 = (b0     < sb) ? partials[b0]     : 0;
            int a1 = (b0 + 1 < sb) ? partials[b0 + 1] : 0;
            int a2 = (b0 + 2 < sb) ? partials[b0 + 2] : 0;
            int a3 = (b0 + 3 < sb) ? partials[b0 + 3] : 0;
            int tsum = a0 + a1 + a2 + a3;
            __syncthreads();
            s[t] = tsum;
            __syncthreads();
            for (int d = 1; d < 256; d <<= 1) {
                int u = (t >= d) ? s[t - d] : 0;
                __syncthreads();
                s[t] += u;
                __syncthreads();
            }
            int excl = s[t] - tsum;
            if (b0     < sb) partials[b0]     = excl;
            if (b0 + 1 < sb) partials[b0 + 1] = excl + a0;
            if (b0 + 2 < sb) partials[b0 + 2] = excl + a0 + a1;
            if (b0 + 3 < sb) partials[b0 + 3] = excl + a0 + a1 + a2;
            if (t == 255) offsets[n] = s[255];
        }
    } else {
        int bi = ((int)blockIdx.x - sb) * 2 + (threadIdx.x >> 7);
        if (bi >= 3 * NCOMBO) return;
        int r  = bi / NCOMBO;
        if (r < 2 && init0[0] == 0.0f) return;
        int cb = bi - r * NCOMBO;
        int a  = cb / 378;
        int rm = cb - a * 378;
        int b  = rm / 54;
        rm -= b * 54;
        int c  = rm / 18;
        int d  = rm - c * 18;
        int j  = threadIdx.x & 127;
        const float* Ur = U + r * 34 * WIDTH;
        Uc[(size_t)bi * WIDTH + j] = Ur[a * WIDTH + j] + Ur[(6 + b) * WIDTH + j]
                                   + Ur[(13 + c) * WIDTH + j] + Ur[(16 + d) * WIDTH + j];
    }
}

// ---------------------------------------------------------------------------
// F3: blocks [0,gb): gemm12 (pre GEMM + LN + 2/4 output GEMMs, coalesced).
//     blocks [gb,gb+eb): scatter (offsets computed inline — no dependency).
//     blocks [gb+eb,...): scan3 (write offsets[] for k_agg).
// ---------------------------------------------------------------------------
__global__ void __launch_bounds__(256, 2) k_f3(
        const float* __restrict__ x,
        const short* __restrict__ preF, const float* __restrict__ pre_b,
        const short* __restrict__ w0F, const float* __restrict__ b0,
        const short* __restrict__ w1F, const float* __restrict__ b1,
        const short* __restrict__ w2F, const float* __restrict__ b2,
        const short* __restrict__ w3F, const float* __restrict__ b3,
        const float* __restrict__ scal,
        short* __restrict__ Gb, float* __restrict__ A,
        short* __restrict__ Bb, short* __restrict__ Cb, int n,
        const int* __restrict__ edge_index, const int* __restrict__ edge_attr,
        const int* __restrict__ counts, const int* __restrict__ lscan,
        const int* __restrict__ partials, const int* __restrict__ rank,
        int* __restrict__ offsets, unsigned* __restrict__ s_pk, int E,
        int gb, int eb) {
    __shared__ short xs_raw[64 * XSL];
    __shared__ short xs_xx[64 * XSL];
    int tid = threadIdx.x;

    if ((int)blockIdx.x >= gb) {
        int rb = (int)blockIdx.x - gb;
        if (rb < eb) {
            // ---- scatter ----
            int e = rb * 256 + tid;
            if (e >= E) return;
            int src = edge_index[e];
            int dst = edge_index[E + e];
            int4 at = ((const int4*)edge_attr)[e];
            int combo = ((at.x * 7 + at.y) * 3 + at.z) * 18 + at.w;
            int off = partials[dst >> 8] + lscan[dst] - counts[dst];
            s_pk[off + rank[e]] = (unsigned)src | ((unsigned)combo << 17);
        } else {
            // ---- scan3: offsets[i] for k_agg ----
            int i = (rb - eb) * 256 + tid;
            if (i >= n) return;
            offsets[i] = partials[i >> 8] + lscan[i] - counts[i];
        }
        return;
    }

    // ---- gemm12 ----
    int w    = tid >> 6;
    int lane = tid & 63;
    int quad = lane >> 4, l16 = lane & 15;
    int m0   = blockIdx.x * 64;

    bf16x8 Bg[2][4], Bc[2][4];
#pragma unroll
    for (int tt = 0; tt < 2; ++tt)
#pragma unroll
        for (int kc = 0; kc < 4; ++kc) {
            int fo = (((2 * w + tt) * 4 + kc) * 64 + lane) * 8;
            Bg[tt][kc] = *(const bf16x8*)(w0F + fo);
            Bc[tt][kc] = *(const bf16x8*)(w3F + fo);
        }

#pragma unroll
    for (int it = 0; it < 8; ++it) {
        int fi  = it * 256 + tid;
        int row = fi >> 5, c4 = fi & 31;
        int gr  = min(m0 + row, n - 1);
        float4 v = ((const float4*)x)[(size_t)gr * 32 + c4];
        uint2 p;
        p.x = pack2(v.x, v.y);
        p.y = pack2(v.z, v.w);
        *(uint2*)(&xs_raw[row * XSL + c4 * 4]) = p;
    }
    __syncthreads();

    {
        bf16x8 a[4];
#pragma unroll
        for (int kc = 0; kc < 4; ++kc)
            a[kc] = *(const bf16x8*)(&xs_raw[(w * 16 + l16) * XSL + kc * 32 + quad * 8]);
        f32x4 acc[8];
#pragma unroll
        for (int t = 0; t < 8; ++t) acc[t] = (f32x4){0.f, 0.f, 0.f, 0.f};
#pragma unroll
        for (int kc = 0; kc < 4; ++kc)
#pragma unroll
            for (int t = 0; t < 8; ++t) {
                bf16x8 b = *(const bf16x8*)(preF + ((t * 4 + kc) * 64 + lane) * 8);
                acc[t] = __builtin_amdgcn_mfma_f32_16x16x32_bf16(a[kc], b, acc[t], 0, 0, 0);
            }
#pragma unroll
        for (int t = 0; t < 8; ++t) {
            float bv = pre_b[t * 16 + l16];
#pragma unroll
            for (int r = 0; r < 4; ++r) acc[t][r] += bv;
        }
#pragma unroll
        for (int r = 0; r < 4; ++r) {
            float s = 0.f, s2 = 0.f;
#pragma unroll
            for (int t = 0; t < 8; ++t) { float v = acc[t][r]; s += v; s2 += v * v; }
            s  += __shfl_xor(s, 1);  s2 += __shfl_xor(s2, 1);
            s  += __shfl_xor(s, 2);  s2 += __shfl_xor(s2, 2);
            s  += __shfl_xor(s, 4);  s2 += __shfl_xor(s2, 4);
            s  += __shfl_xor(s, 8);  s2 += __shfl_xor(s2, 8);
            float m   = s * (1.0f / WIDTH);
            float var = s2 * (1.0f / WIDTH) - m * m;
            float rs  = rsqrtf(var + 1e-5f);
#pragma unroll
            for (int t = 0; t < 8; ++t) acc[t][r] = (acc[t][r] - m) * rs;
        }
        int rowb = w * 16 + quad * 4;
#pragma unroll
        for (int t = 0; t < 8; ++t)
#pragma unroll
            for (int r = 0; r < 4; ++r)
                xs_xx[(rowb + r) * XSL + t * 16 + l16] = f2b(acc[t][r]);
    }
    __syncthreads();

    bf16x8 a2[4][4];
#pragma unroll
    for (int i = 0; i < 4; ++i)
#pragma unroll
        for (int kc = 0; kc < 4; ++kc)
            a2[i][kc] = *(const bf16x8*)(&xs_xx[(i * 16 + l16) * XSL + kc * 32 + quad * 8]);
    __syncthreads();

    {
        f32x4 accG[4][2], accC[4][2];
#pragma unroll
        for (int i = 0; i < 4; ++i)
#pragma unroll
            for (int tt = 0; tt < 2; ++tt) {
                accG[i][tt] = (f32x4){0.f,0.f,0.f,0.f};
                accC[i][tt] = (f32x4){0.f,0.f,0.f,0.f};
            }
#pragma unroll
        for (int kc = 0; kc < 4; ++kc)
#pragma unroll
            for (int i = 0; i < 4; ++i)
#pragma unroll
                for (int tt = 0; tt < 2; ++tt) {
                    accG[i][tt] = __builtin_amdgcn_mfma_f32_16x16x32_bf16(a2[i][kc], Bg[tt][kc], accG[i][tt], 0, 0, 0);
                    accC[i][tt] = __builtin_amdgcn_mfma_f32_16x16x32_bf16(a2[i][kc], Bc[tt][kc], accC[i][tt], 0, 0, 0);
                }
#pragma unroll
        for (int tt = 0; tt < 2; ++tt) {
            int col = (2 * w + tt) * 16 + l16;
            float bg = b0[col];
            float bc = b3[col];
#pragma unroll
            for (int i = 0; i < 4; ++i)
#pragma unroll
                for (int r = 0; r < 4; ++r) {
                    int row = i * 16 + quad * 4 + r;
                    xs_raw[row * XSL + col] = f2b(gelu_fast(accG[i][tt][r] + bg));
                    xs_xx[row * XSL + col]  = f2b(accC[i][tt][r] + bc);
                }
        }
    }
    __syncthreads();

#pragma unroll
    for (int it = 0; it < 4; ++it) {
        int si  = it * 256 + tid;
        int row = si >> 4, c8 = si & 15;
        if (m0 + row < n) {
            *(bf16x8*)(Gb + (size_t)(m0 + row) * WIDTH + c8 * 8) = *(const bf16x8*)(&xs_raw[row * XSL + c8 * 8]);
            *(bf16x8*)(Cb + (size_t)(m0 + row) * WIDTH + c8 * 8) = *(const bf16x8*)(&xs_xx[row * XSL + c8 * 8]);
        }
    }

    if (scal[0] != 0.0f) {
        bf16x8 Ba[2][4], Bbf[2][4];
#pragma unroll
        for (int tt = 0; tt < 2; ++tt)
#pragma unroll
            for (int kc = 0; kc < 4; ++kc) {
                int fo = (((2 * w + tt) * 4 + kc) * 64 + lane) * 8;
                Ba[tt][kc]  = *(const bf16x8*)(w1F + fo);
                Bbf[tt][kc] = *(const bf16x8*)(w2F + fo);
            }
        f32x4 accA[4][2], accB[4][2];
#pragma unroll
        for (int i = 0; i < 4; ++i)
#pragma unroll
            for (int tt = 0; tt < 2; ++tt) {
                accA[i][tt] = (f32x4){0.f,0.f,0.f,0.f};
                accB[i][tt] = (f32x4){0.f,0.f,0.f,0.f};
            }
#pragma unroll
        for (int kc = 0; kc < 4; ++kc)
#pragma unroll
            for (int i = 0; i < 4; ++i)
#pragma unroll
                for (int tt = 0; tt < 2; ++tt) {
                    accA[i][tt] = __builtin_amdgcn_mfma_f32_16x16x32_bf16(a2[i][kc], Ba[tt][kc],  accA[i][tt], 0, 0, 0);
                    accB[i][tt] = __builtin_amdgcn_mfma_f32_16x16x32_bf16(a2[i][kc], Bbf[tt][kc], accB[i][tt], 0, 0, 0);
                }
#pragma unroll
        for (int tt = 0; tt < 2; ++tt) {
            int col = (2 * w + tt) * 16 + l16;
            float ba = b1[col];
            float bb = b2[col];
#pragma unroll
            for (int i = 0; i < 4; ++i)
#pragma unroll
                for (int r = 0; r < 4; ++r) {
                    int row = m0 + i * 16 + quad * 4 + r;
                    if (row < n) {
                        size_t idx = (size_t)row * WIDTH + col;
                        A[idx]  = accA[i][tt][r] + ba;
                        Bb[idx] = f2b(accB[i][tt][r] + bb);
                    }
                }
        }
    }
}

// ---------------------------------------------------------------------------
// k_agg: one wave per node.  FAST PATH: 2 edges per wave — half h (lanes
// [h*32, h*32+32)) processes edge p+h; lane col-group c = L&31 owns cols
// {4c..4c+3}.  Halves the per-node serial rounds and the VMEM instruction
// count (Cb uint2 + U2c float4 per lane) → 2x memory-level parallelism.
// Cross-half combine at the end via 4 shfl_xor(32).  Slow (attention) path
// keeps the 1-edge full-wave layout.
// ---------------------------------------------------------------------------
__global__ void __launch_bounds__(256)
k_agg(const int* __restrict__ offsets, const unsigned* __restrict__ s_pk,
      const float* __restrict__ A, const short* __restrict__ Bb,
      const short* __restrict__ Cb, const float* __restrict__ Uc,
      const float* __restrict__ scal, const short* __restrict__ Gb,
      short* __restrict__ hb, int n) {
    int wid = threadIdx.x >> 6;
    int L   = threadIdx.x & 63;
    int node = blockIdx.x * 4 + wid;
    if (node >= n) return;
    int start = __builtin_amdgcn_readfirstlane(offsets[node]);
    int end   = __builtin_amdgcn_readfirstlane(offsets[node + 1]);

    const unsigned* Cb32 = (const unsigned*)Cb;
    const unsigned* Bb32 = (const unsigned*)Bb;
    const float* U2c = Uc + 2 * (size_t)NCOMBO * WIDTH;
    const float2* U0c2 = (const float2*)(Uc);
    const float2* U1c2 = (const float2*)(Uc + (size_t)NCOMBO * WIDTH);
    const float2* U2c2 = (const float2*)U2c;

    float i0 = scal[0], i1 = scal[1];

    if (i0 == 0.0f) {
        int h = L >> 5;   // which edge of the pair
        int c = L & 31;   // col group: cols 4c..4c+3
        float a0 = 0.f, a1 = 0.f, a2 = 0.f, a3 = 0.f;
        int p = start;
        for (; p + 4 <= end; p += 4) {
            unsigned pa0 = __builtin_amdgcn_readfirstlane(s_pk[p]);
            unsigned pb0 = __builtin_amdgcn_readfirstlane(s_pk[p + 1]);
            unsigned pa1 = __builtin_amdgcn_readfirstlane(s_pk[p + 2]);
            unsigned pb1 = __builtin_amdgcn_readfirstlane(s_pk[p + 3]);
            unsigned pk0 = h ? pb0 : pa0;
            unsigned pk1 = h ? pb1 : pa1;
            uint2  cc0 = *(const uint2*)(Cb32 + ((size_t)(pk0 & 0x1FFFFu) << 6) + 2 * c);
            uint2  cc1 = *(const uint2*)(Cb32 + ((size_t)(pk1 & 0x1FFFFu) << 6) + 2 * c);
            float4 uu0 = ((const float4*)(U2c + ((size_t)(pk0 >> 17) << 7)))[c];
            float4 uu1 = ((const float4*)(U2c + ((size_t)(pk1 >> 17) << 7)))[c];
            a0 += gelu_fast(b2f_lo(cc0.x) + uu0.x);
            a1 += gelu_fast(b2f_hi(cc0.x) + uu0.y);
            a2 += gelu_fast(b2f_lo(cc0.y) + uu0.z);
            a3 += gelu_fast(b2f_hi(cc0.y) + uu0.w);
            a0 += gelu_fast(b2f_lo(cc1.x) + uu1.x);
            a1 += gelu_fast(b2f_hi(cc1.x) + uu1.y);
            a2 += gelu_fast(b2f_lo(cc1.y) + uu1.z);
            a3 += gelu_fast(b2f_hi(cc1.y) + uu1.w);
        }
        if (p + 2 <= end) {
            unsigned pa0 = __builtin_amdgcn_readfirstlane(s_pk[p]);
            unsigned pb0 = __builtin_amdgcn_readfirstlane(s_pk[p + 1]);
            unsigned pk0 = h ? pb0 : pa0;
            uint2  cc0 = *(const uint2*)(Cb32 + ((size_t)(pk0 & 0x1FFFFu) << 6) + 2 * c);
            float4 uu0 = ((const float4*)(U2c + ((size_t)(pk0 >> 17) << 7)))[c];
            a0 += gelu_fast(b2f_lo(cc0.x) + uu0.x);
            a1 += gelu_fast(b2f_hi(cc0.x) + uu0.y);
            a2 += gelu_fast(b2f_lo(cc0.y) + uu0.z);
            a3 += gelu_fast(b2f_hi(cc0.y) + uu0.w);
            p += 2;
        }
        if (p < end) {
            // single tail edge: both halves load it; only h==0 accumulates
            unsigned pk0 = __builtin_amdgcn_readfirstlane(s_pk[p]);
            uint2  cc0 = *(const uint2*)(Cb32 + ((size_t)(pk0 & 0x1FFFFu) << 6) + 2 * c);
            float4 uu0 = ((const float4*)(U2c + ((size_t)(pk0 >> 17) << 7)))[c];
            if (h == 0) {
                a0 += gelu_fast(b2f_lo(cc0.x) + uu0.x);
                a1 += gelu_fast(b2f_hi(cc0.x) + uu0.y);
                a2 += gelu_fast(b2f_lo(cc0.y) + uu0.z);
                a3 += gelu_fast(b2f_hi(cc0.y) + uu0.w);
            }
        }
        // combine the two halves (each lane pairs with lane^32, same c)
        a0 += __shfl_xor(a0, 32);
        a1 += __shfl_xor(a1, 32);
        a2 += __shfl_xor(a2, 32);
        a3 += __shfl_xor(a3, 32);
        float sE = __expf(i1);
        if (h == 0) {
            uint2 g = *(const uint2*)((const unsigned*)Gb + (size_t)node * 64 + 2 * c);
            uint2 o;
            o.x = pack2(b2f_lo(g.x) + a0 * sE, b2f_hi(g.x) + a1 * sE);
            o.y = pack2(b2f_lo(g.y) + a2 * sE, b2f_hi(g.y) + a3 * sE);
            *(uint2*)((unsigned*)hb + (size_t)node * 64 + 2 * c) = o;
        }
    } else {
        float acc0 = 0.0f, acc1 = 0.0f;
        float2 av = *(const float2*)(A + (size_t)node * WIDTH + 2 * L);
        int p = start;
        for (; p + 2 <= end; p += 2) {
            unsigned pk0 = s_pk[p], pk1 = s_pk[p + 1];
            unsigned sA = pk0 & 0x1FFFFu, cA = pk0 >> 17;
            unsigned sB = pk1 & 0x1FFFFu, cB = pk1 >> 17;
            float2 u0a = U0c2[cA * 64 + L], u0b = U0c2[cB * 64 + L];
            float2 u1a = U1c2[cA * 64 + L], u1b = U1c2[cB * 64 + L];
            float2 u2a = U2c2[cA * 64 + L], u2b = U2c2[cB * 64 + L];
            unsigned bba = Bb32[sA * 64 + L], bbb = Bb32[sB * 64 + L];
            unsigned cca = Cb32[sA * 64 + L], ccb = Cb32[sB * 64 + L];
            {
                float q0 = av.x + u0a.x, q1 = av.y + u0a.y;
                float k0 = b2f_lo(bba) + u1a.x, k1 = b2f_hi(bba) + u1a.y;
                float v0 = gelu_fast(b2f_lo(cca) + u2a.x);
                float v1 = gelu_fast(b2f_hi(cca) + u2a.y);
                float s = q0 * k0 + q1 * k1;
                s += __shfl_xor(s, 1);
                s += __shfl_xor(s, 2);
                s += __shfl_xor(s, 4);
                s += __shfl_xor(s, 8);
                s += __shfl_xor(s, 16);
                float att = __expf(s * 0.125f * i0 + i1);
                acc0 += v0 * att;
                acc1 += v1 * att;
            }
            {
                float q0 = av.x + u0b.x, q1 = av.y + u0b.y;
                float k0 = b2f_lo(bbb) + u1b.x, k1 = b2f_hi(bbb) + u1b.y;
                float v0 = gelu_fast(b2f_lo(ccb) + u2b.x);
                float v1 = gelu_fast(b2f_hi(ccb) + u2b.y);
                float s = q0 * k0 + q1 * k1;
                s += __shfl_xor(s, 1);
                s += __shfl_xor(s, 2);
                s += __shfl_xor(s, 4);
                s += __shfl_xor(s, 8);
                s += __shfl_xor(s, 16);
                float att = __expf(s * 0.125f * i0 + i1);
                acc0 += v0 * att;
                acc1 += v1 * att;
            }
        }
        if (p < end) {
            unsigned pk = s_pk[p];
            unsigned sA = pk & 0x1FFFFu, cA = pk >> 17;
            float2 u0 = U0c2[cA * 64 + L];
            float2 u1 = U1c2[cA * 64 + L];
            float2 u2 = U2c2[cA * 64 + L];
            unsigned bb = Bb32[sA * 64 + L];
            unsigned cc = Cb32[sA * 64 + L];
            float q0 = av.x + u0.x, q1 = av.y + u0.y;
            float k0 = b2f_lo(bb) + u1.x, k1 = b2f_hi(bb) + u1.y;
            float v0 = gelu_fast(b2f_lo(cc) + u2.x);
            float v1 = gelu_fast(b2f_hi(cc) + u2.y);
            float s = q0 * k0 + q1 * k1;
            s += __shfl_xor(s, 1);
            s += __shfl_xor(s, 2);
            s += __shfl_xor(s, 4);
            s += __shfl_xor(s, 8);
            s += __shfl_xor(s, 16);
            float att = __expf(s * 0.125f * i0 + i1);
            acc0 += v0 * att;
            acc1 += v1 * att;
        }
        unsigned g = ((const unsigned*)Gb)[(size_t)node * 64 + L];
        ((unsigned*)hb)[(size_t)node * 64 + L] = pack2(b2f_lo(g) + acc0, b2f_hi(g) + acc1);
    }
}

// ---------------------------------------------------------------------------
// k_post: coop-load hb -> LDS, B-stationary MFMA, staged coalesced out.
// ---------------------------------------------------------------------------
__global__ void __launch_bounds__(256, 2) k_post(
        const float* __restrict__ x, const short* __restrict__ hb,
        const short* __restrict__ postF, const float* __restrict__ post_b,
        float* __restrict__ out, int n) {
    __shared__ short hs[64 * XSL];
    __shared__ float os[64 * OSL];
    int tid  = threadIdx.x;
    int w    = tid >> 6;
    int lane = tid & 63;
    int quad = lane >> 4, l16 = lane & 15;
    int m0   = blockIdx.x * 64;

    bf16x8 Bp[2][4];
#pragma unroll
    for (int tt = 0; tt < 2; ++tt)
#pragma unroll
        for (int kc = 0; kc < 4; ++kc)
            Bp[tt][kc] = *(const bf16x8*)(postF + (((2 * w + tt) * 4 + kc) * 64 + lane) * 8);

#pragma unroll
    for (int it = 0; it < 4; ++it) {
        int si  = it * 256 + tid;
        int row = si >> 4, c8 = si & 15;
        int gr  = min(m0 + row, n - 1);
        *(bf16x8*)(&hs[row * XSL + c8 * 8]) = *(const bf16x8*)(hb + (size_t)gr * WIDTH + c8 * 8);
    }
    __syncthreads();

    bf16x8 a[4][4];
#pragma unroll
    for (int i = 0; i < 4; ++i)
#pragma unroll
        for (int kc = 0; kc < 4; ++kc)
            a[i][kc] = *(const bf16x8*)(&hs[(i * 16 + l16) * XSL + kc * 32 + quad * 8]);

    f32x4 acc[4][2];
#pragma unroll
    for (int i = 0; i < 4; ++i)
#pragma unroll
        for (int tt = 0; tt < 2; ++tt) acc[i][tt] = (f32x4){0.f,0.f,0.f,0.f};
#pragma unroll
    for (int kc = 0; kc < 4; ++kc)
#pragma unroll
        for (int i = 0; i < 4; ++i)
#pragma unroll
            for (int tt = 0; tt < 2; ++tt)
                acc[i][tt] = __builtin_amdgcn_mfma_f32_16x16x32_bf16(a[i][kc], Bp[tt][kc], acc[i][tt], 0, 0, 0);

#pragma unroll
    for (int tt = 0; tt < 2; ++tt) {
        int col = (2 * w + tt) * 16 + l16;
        float bv = post_b[col];
#pragma unroll
        for (int i = 0; i < 4; ++i)
#pragma unroll
            for (int r = 0; r < 4; ++r)
                os[(i * 16 + quad * 4 + r) * OSL + col] = acc[i][tt][r] + bv;
    }
    __syncthreads();

#pragma unroll
    for (int it = 0; it < 8; ++it) {
        int fi  = it * 256 + tid;
        int row = fi >> 5, c4 = fi & 31;
        if (m0 + row < n) {
            float4 xv = ((const float4*)x)[(size_t)(m0 + row) * 32 + c4];
            float4 av = *(const float4*)(&os[row * OSL + c4 * 4]);
            float4 ov = {xv.x + av.x, xv.y + av.y, xv.z + av.z, xv.w + av.w};
            ((float4*)out)[(size_t)(m0 + row) * 32 + c4] = ov;
        }
    }
}

extern "C" void kernel_launch(void* const* d_in, const int* in_sizes, int n_in,
                              void* d_out, int out_size, void* d_ws, size_t ws_size,
                              hipStream_t stream) {
    const float* x      = (const float*)d_in[0];
    const int*   eidx   = (const int*)d_in[1];
    const int*   eattr  = (const int*)d_in[2];
    const float* pre_w  = (const float*)d_in[3];
    const float* pre_b  = (const float*)d_in[4];
    const float* msg0_w = (const float*)d_in[5];
    const float* msg0_b = (const float*)d_in[6];
    const float* msg1_w = (const float*)d_in[7];
    const float* msg1_b = (const float*)d_in[8];
    const float* msg2_w = (const float*)d_in[9];
    const float* msg2_b = (const float*)d_in[10];
    const float* msg3_w = (const float*)d_in[11];
    const float* msg3_b = (const float*)d_in[12];
    const float* r0w    = (const float*)d_in[13];
    const float* r0b    = (const float*)d_in[14];
    const float* r1w    = (const float*)d_in[15];
    const float* r1b    = (const float*)d_in[16];
    const float* r2w    = (const float*)d_in[17];
    const float* r2b    = (const float*)d_in[18];
    const float* post_w = (const float*)d_in[19];
    const float* post_b = (const float*)d_in[20];
    const float* emb0   = (const float*)d_in[21];
    const float* emb1   = (const float*)d_in[22];
    const float* emb2   = (const float*)d_in[23];
    const float* emb3   = (const float*)d_in[24];
    const float* einit  = (const float*)d_in[25];
    const float* init0  = (const float*)d_in[26];

    int n = in_sizes[0] / WIDTH;
    int E = in_sizes[2] / 4;
    size_t NW = (size_t)n * WIDTH;

    float* ws   = (float*)d_ws;
    float* A    = ws;                              // [N,128] f32 (full path only)
    float* U    = ws + NW;                         // [3][34][128]
    float* Uc   = U + 3 * 34 * WIDTH;              // [3][NCOMBO][128]
    float* scal = Uc + 3 * (size_t)NCOMBO * WIDTH; // [2]
    short* sw   = (short*)(scal + 2);
    short* preF  = sw;                             // 6 x 16384 bf16 frag-order weights
    short* w0F   = sw + 16384;
    short* w1F   = sw + 2 * 16384;
    short* w2F   = sw + 3 * 16384;
    short* w3F   = sw + 4 * 16384;
    short* postF = sw + 5 * 16384;
    short* Bb    = sw + 6 * 16384;                 // [N,128] bf16 (full path)
    short* Cb    = Bb + NW;                        // [N,128] bf16
    short* Gb    = Cb + NW;                        // [N,128] bf16
    short* hb    = Gb + NW;                        // [N,128] bf16
    int*      ib       = (int*)(hb + NW);
    int*      offsets  = ib;                       // n+1
    int*      counts   = offsets + (n + 1);        // n
    int*      lscan    = counts + n;               // n
    int*      partials = lscan + n;                // <=1024
    int*      rank     = partials + 1024;          // E
    unsigned* s_pk     = (unsigned*)(rank + E);    // E
    int*      done     = (int*)(s_pk + E);         // 1 (scan2 last-block flag)

    hipMemsetAsync(counts, 0, (size_t)n * sizeof(int), stream);

    // F1: weight swizzle + U tables + hist(rank) + done reset
    int f1_total = TOTW + TOTU + E;
    k_f1<<<(f1_total + 255) / 256, 256, 0, stream>>>(
        einit, init0, emb0, emb1, emb2, emb3,
        r0w, r0b, r1w, r1b, r2w, r2b,
        pre_w, msg0_w, msg1_w, msg2_w, msg3_w, post_w,
        preF, w0F, w1F, w2F, w3F, postF, U, scal,
        eidx, counts, rank, done, E);

    // F2: scan1 (+ last-block scan2 tail) + prepc
    int sb  = (n + 255) / 256;
    int pcb = (3 * NCOMBO + 1) / 2;
    k_f2<<<sb + pcb, 256, 0, stream>>>(counts, lscan, partials, n, sb, U, init0, Uc,
                                       done, offsets);

    // F3: gemm12 + scatter (inline offsets) + scan3
    int gb = (n + 63) / 64;
    int eb = (E + 255) / 256;
    k_f3<<<gb + eb + sb, 256, 0, stream>>>(
        x, preF, pre_b, w0F, msg0_b, w1F, msg1_b, w2F, msg2_b, w3F, msg3_b,
        scal, Gb, A, Bb, Cb, n,
        eidx, eattr, counts, lscan, partials, rank, offsets, s_pk, E, gb, eb);

    k_agg<<<(n + 3) / 4, 256, 0, stream>>>(offsets, s_pk, A, Bb, Cb, Uc, scal, Gb, hb, n);
    k_post<<<gb, 256, 0, stream>>>(x, hb, postF, post_b, (float*)d_out, n);
}